// Round 10
// baseline (209.398 us; speedup 1.0000x reference)
//
#include <hip/hip_runtime.h>
#include <hip/hip_bf16.h>
#include <math.h>

#define Bb 2
#define Ss 2048
#define Ee 1024
#define Hh 16
#define HDd 64
#define NEG_INF_F -1000000000.0f

typedef __attribute__((ext_vector_type(8))) short bfrag;     // 8 bf16
typedef __attribute__((ext_vector_type(4))) float ffrag;     // 16x16 C/D
typedef __attribute__((ext_vector_type(16))) float ffrag16;  // 32x32 C/D
typedef __attribute__((ext_vector_type(8))) unsigned short us8;

#define C1F 0.1803368801f  /* 0.125 * log2(e) — folded into Q at gemm_qkv */

// s_waitcnt immediates: vmcnt[3:0]|expcnt[6:4]|lgkmcnt[11:8]
// (expcnt=7, lgkmcnt=15 -> "ignore"), vmcnt = 6 / 0.
#define WAIT_VM6   0x0F76
#define WAIT_VM0   0x0F70

// ---- bf16 helpers ----------------------------------------------------------
__device__ __forceinline__ unsigned short f2bf(float x) {
  unsigned u = __float_as_uint(x);
  u += 0x7fffu + ((u >> 16) & 1u);
  return (unsigned short)(u >> 16);
}
__device__ __forceinline__ float bf2f(unsigned short h) {
  return __uint_as_float(((unsigned)h) << 16);
}

__device__ __forceinline__ void async_copy16(void* lds, const void* g) {
  __builtin_amdgcn_global_load_lds(
      (const __attribute__((address_space(1))) unsigned int*)g,
      (__attribute__((address_space(3))) unsigned int*)lds, 16, 0, 0);
}

// ---------------------------------------------------------------------------
// Fused split pass: x (4M) -> hi only; Wqkv (3M), Wout (1M) -> hi/lo.
// ---------------------------------------------------------------------------
__global__ __launch_bounds__(256) void split_all(
    const float* __restrict__ x, unsigned short* __restrict__ xh,
    const float* __restrict__ wq, unsigned short* __restrict__ wqh,
    unsigned short* __restrict__ wql,
    const float* __restrict__ wo, unsigned short* __restrict__ woh,
    unsigned short* __restrict__ wol) {
  int bid = blockIdx.x;
  const float* in;
  unsigned short *hi, *lo;
  if (bid < 4096) { in = x; hi = xh; lo = nullptr; }
  else if (bid < 7168) { bid -= 4096; in = wq; hi = wqh; lo = wql; }
  else { bid -= 7168; in = wo; hi = woh; lo = wol; }
  const int idx = (bid * 256 + threadIdx.x) * 4;
  const float4 v = *(const float4*)(in + idx);
  unsigned short h0 = f2bf(v.x), h1 = f2bf(v.y), h2 = f2bf(v.z), h3 = f2bf(v.w);
  ushort4 hv = {h0, h1, h2, h3};
  *(ushort4*)(hi + idx) = hv;
  if (lo) {
    ushort4 lv = {f2bf(v.x - bf2f(h0)), f2bf(v.y - bf2f(h1)),
                  f2bf(v.z - bf2f(h2)), f2bf(v.w - bf2f(h3))};
    *(ushort4*)(lo + idx) = lv;
  }
}

// ---------------------------------------------------------------------------
// LDS slot map (rows of 32 bf16 = 4 x 16B chunks):
// slot(row,q) = (row>>1)*8 + ((((row&1)*4)|q) ^ ((row>>1)&7)).
// ---------------------------------------------------------------------------
__device__ __forceinline__ int gemm_slot(int row, int q) {
  return (row >> 1) * 8 + ((((row & 1) * 4) | q) ^ ((row >> 1) & 7));
}
__device__ __forceinline__ int slot_src_off(int slot, int ld) {
  const int dr = slot >> 3;
  const int idx8 = (slot & 7) ^ (dr & 7);
  const int row = dr * 2 + (idx8 >> 2);
  const int q = idx8 & 3;
  return row * ld + q * 8;
}

// ---------------------------------------------------------------------------
// QKV GEMM, 32x32x16 core: C = xh * (Wh + Wl)^T + bias (2 MFMAs/product).
// 128x128 tile. TRIPLE-buffered counted-vmcnt pipeline (R4/R9 measured-best
// form, ~60.0us): per iter, wait vmcnt(6) -> s_barrier -> sched_barrier ->
// prefetch k+2 -> compute k. LDS 3 x 24KB = 72KB.
// Epilogue (all single bf16): Q pre-scaled by C1F -> [bh][s][64];
// K -> [bh][s][64]; V^T -> [bh][d][s].
// ---------------------------------------------------------------------------
__global__ __launch_bounds__(256) void gemm_qkv(
    const unsigned short* __restrict__ Ah,
    const unsigned short* __restrict__ Bh, const unsigned short* __restrict__ Bl,
    const float* __restrict__ bias,
    unsigned short* __restrict__ q_h, unsigned short* __restrict__ k_h,
    unsigned short* __restrict__ vt_h) {
  __shared__ unsigned short sm[3 * 12288];  // 3 stage sets of (A|Bh|Bl) = 72KB
  const int tid = threadIdx.x;
  const int lane = tid & 63;
  const int w = tid >> 6;
  const int wm = w >> 1;
  const int wn = w & 1;
  const int l31 = lane & 31;
  const int e = lane >> 5;
  const int m0 = blockIdx.x * 128;
  const int n0 = blockIdx.y * 128;

  int coff[2], ldsb[2];
#pragma unroll
  for (int u = 0; u < 2; ++u) {
    const int slot = w * 128 + u * 64 + lane;
    coff[u] = slot_src_off(slot, 1024);
    ldsb[u] = (w * 128 + u * 64) * 8;
  }
  const unsigned short* srcs[3] = {
      Ah + (size_t)m0 * 1024, Bh + (size_t)n0 * 1024, Bl + (size_t)n0 * 1024};

  ffrag16 acc[2][2];
#pragma unroll
  for (int i = 0; i < 2; ++i)
#pragma unroll
    for (int j = 0; j < 2; ++j) acc[i][j] = (ffrag16)0.f;

  int ca[2][2], cb[2][2];
#pragma unroll
  for (int t = 0; t < 2; ++t)
#pragma unroll
    for (int h2 = 0; h2 < 2; ++h2) {
      ca[t][h2] = gemm_slot(wm * 64 + t * 32 + l31, h2 * 2 + e) * 8;
      cb[t][h2] = gemm_slot(wn * 64 + t * 32 + l31, h2 * 2 + e) * 8;
    }

  // prologue: stage tile 0 -> buf0, tile 1 -> buf1 (6 ordered DMAs each)
#pragma unroll
  for (int t = 0; t < 3; ++t)
#pragma unroll
    for (int u = 0; u < 2; ++u)
      async_copy16(&sm[0 + t * 4096 + ldsb[u]], srcs[t] + coff[u] + 0);
#pragma unroll
  for (int t = 0; t < 3; ++t)
#pragma unroll
    for (int u = 0; u < 2; ++u)
      async_copy16(&sm[12288 + t * 4096 + ldsb[u]], srcs[t] + coff[u] + 32);

  int b0 = 0, b1 = 12288, b2 = 24576;  // cur / next / prefetch-target (shorts)
  for (int k = 0; k < 32; ++k) {
    // wait own-wave DMA for tile k (oldest 6), keep tile k+1's 6 in flight
    if (k < 31) __builtin_amdgcn_s_waitcnt(WAIT_VM6);
    else        __builtin_amdgcn_s_waitcnt(WAIT_VM0);
    __builtin_amdgcn_s_barrier();
    __builtin_amdgcn_sched_barrier(0);
    if (k + 2 < 32) {  // prefetch distance 2 into buffer read at iter k-1
      const int k0 = (k + 2) * 32;
#pragma unroll
      for (int t = 0; t < 3; ++t)
#pragma unroll
        for (int u = 0; u < 2; ++u)
          async_copy16(&sm[b2 + t * 4096 + ldsb[u]], srcs[t] + coff[u] + k0);
    }

    bfrag ah[2][2], bhf[2][2], blf[2][2];
#pragma unroll
    for (int t = 0; t < 2; ++t)
#pragma unroll
      for (int h2 = 0; h2 < 2; ++h2) {
        ah[t][h2] = *(const bfrag*)&sm[b0 + 0 + ca[t][h2]];
        bhf[t][h2] = *(const bfrag*)&sm[b0 + 4096 + cb[t][h2]];
        blf[t][h2] = *(const bfrag*)&sm[b0 + 8192 + cb[t][h2]];
      }
#pragma unroll
    for (int mt = 0; mt < 2; ++mt)
#pragma unroll
      for (int nt = 0; nt < 2; ++nt)
#pragma unroll
        for (int h2 = 0; h2 < 2; ++h2) {
          acc[mt][nt] = __builtin_amdgcn_mfma_f32_32x32x16_bf16(
              ah[mt][h2], bhf[nt][h2], acc[mt][nt], 0, 0, 0);
          acc[mt][nt] = __builtin_amdgcn_mfma_f32_32x32x16_bf16(
              ah[mt][h2], blf[nt][h2], acc[mt][nt], 0, 0, 0);
        }
    const int tb = b0; b0 = b1; b1 = b2; b2 = tb;  // rotate buffers
  }

#pragma unroll
  for (int nt = 0; nt < 2; ++nt) {
    const int n = n0 + wn * 64 + nt * 32 + l31;
    const float bv = bias[n];
    const int h = n / 192;
    const int c = n - h * 192;
    const int d = c & 63;
#pragma unroll
    for (int mt = 0; mt < 2; ++mt) {
      if (c >= 128) {
#pragma unroll
        for (int g = 0; g < 4; ++g) {
          const int m = m0 + wm * 64 + mt * 32 + g * 8 + e * 4;
          const int bidx = m >> 11;
          const int s = m & 2047;
          ushort4 hv4;
          unsigned short* ph = (unsigned short*)&hv4;
#pragma unroll
          for (int r = 0; r < 4; ++r)
            ph[r] = f2bf(acc[mt][nt][g * 4 + r] + bv);
          const size_t off =
              (size_t)(bidx * 16 + h) * (64 * 2048) + (size_t)d * 2048 + s;
          *(ushort4*)(vt_h + off) = hv4;
        }
      } else {
        const float scale = (c < 64) ? C1F : 1.0f;
        unsigned short* dh = (c < 64) ? q_h : k_h;
#pragma unroll
        for (int g = 0; g < 4; ++g)
#pragma unroll
          for (int r = 0; r < 4; ++r) {
            const int m = m0 + wm * 64 + mt * 32 + g * 8 + e * 4 + r;
            const int bidx = m >> 11;
            const int s = m & 2047;
            const size_t off =
                (size_t)(bidx * 16 + h) * (2048 * 64) + (size_t)s * 64 + d;
            dh[off] = f2bf((acc[mt][nt][g * 4 + r] + bv) * scale);
          }
      }
    }
  }
}

// ---------------------------------------------------------------------------
// Out-proj GEMM: A = vals single bf16, B = Wout hi/lo (2 MFMAs/product).
// 128x64 tile, 512 blocks. SINGLE-buffered (R3 form — measured best).
// Writes fp32+bias directly to out.
// ---------------------------------------------------------------------------
__global__ __launch_bounds__(256) void gemm_out2(
    const unsigned short* __restrict__ A,
    const unsigned short* __restrict__ Bh, const unsigned short* __restrict__ Bl,
    const float* __restrict__ bias, float* __restrict__ out) {
  __shared__ unsigned short sm[8192];
  const int tid = threadIdx.x;
  const int lane = tid & 63;
  const int w = tid >> 6;
  const int wm = w >> 1;
  const int wn = w & 1;
  const int l31 = lane & 31;
  const int e = lane >> 5;
  const int m0 = blockIdx.x * 128;
  const int n0 = blockIdx.y * 64;

  int acoff[2], aldsb[2];
#pragma unroll
  for (int u = 0; u < 2; ++u) {
    const int slot = w * 128 + u * 64 + lane;
    acoff[u] = slot_src_off(slot, 1024);
    aldsb[u] = (w * 128 + u * 64) * 8;
  }
  const int bslot = w * 64 + lane;
  const int bcoff = slot_src_off(bslot, 1024);
  const int bldsb = bslot * 8;

  const unsigned short* Ap  = A + (size_t)m0 * 1024;
  const unsigned short* Bph = Bh + (size_t)n0 * 1024;
  const unsigned short* Bpl = Bl + (size_t)n0 * 1024;

  ffrag16 acc[2];
  acc[0] = (ffrag16)0.f;
  acc[1] = (ffrag16)0.f;

  int ca[2][2], cb[2];
#pragma unroll
  for (int t = 0; t < 2; ++t)
#pragma unroll
    for (int h2 = 0; h2 < 2; ++h2)
      ca[t][h2] = gemm_slot(wm * 64 + t * 32 + l31, h2 * 2 + e) * 8;
#pragma unroll
  for (int h2 = 0; h2 < 2; ++h2)
    cb[h2] = gemm_slot(wn * 32 + l31, h2 * 2 + e) * 8;

  for (int k0 = 0; k0 < 1024; k0 += 32) {
    __syncthreads();
#pragma unroll
    for (int u = 0; u < 2; ++u)
      async_copy16(&sm[0 + aldsb[u]], Ap + acoff[u] + k0);
    async_copy16(&sm[4096 + bldsb], Bph + bcoff + k0);
    async_copy16(&sm[6144 + bldsb], Bpl + bcoff + k0);
    __syncthreads();

    bfrag ah[2][2], bhf[2], blf[2];
#pragma unroll
    for (int t = 0; t < 2; ++t)
#pragma unroll
      for (int h2 = 0; h2 < 2; ++h2)
        ah[t][h2] = *(const bfrag*)&sm[0 + ca[t][h2]];
#pragma unroll
    for (int h2 = 0; h2 < 2; ++h2) {
      bhf[h2] = *(const bfrag*)&sm[4096 + cb[h2]];
      blf[h2] = *(const bfrag*)&sm[6144 + cb[h2]];
    }
#pragma unroll
    for (int mt = 0; mt < 2; ++mt)
#pragma unroll
      for (int h2 = 0; h2 < 2; ++h2) {
        acc[mt] = __builtin_amdgcn_mfma_f32_32x32x16_bf16(
            ah[mt][h2], bhf[h2], acc[mt], 0, 0, 0);
        acc[mt] = __builtin_amdgcn_mfma_f32_32x32x16_bf16(
            ah[mt][h2], blf[h2], acc[mt], 0, 0, 0);
      }
  }

  const int n = n0 + wn * 32 + l31;
  const float bv = bias[n];
#pragma unroll
  for (int mt = 0; mt < 2; ++mt)
#pragma unroll
    for (int g = 0; g < 4; ++g)
#pragma unroll
      for (int r = 0; r < 4; ++r) {
        const int m = m0 + wm * 64 + mt * 32 + g * 8 + e * 4 + r;
        out[(size_t)m * 1024 + n] = acc[mt][g * 4 + r] + bv;
      }
}

// ---------------------------------------------------------------------------
// Single-phase flash attention, 1024 blocks, backfill-balanced.
// R10 theory: attn_2ph was GRID-limited (512 blocks = 2/CU = 8 waves/CU)
// while its 40KB LDS allows exactly 4/CU. R1's pathology was waves idling
// INSIDE live blocks (unequal wave spans in one block), not unequal block
// spans: with one 64-row block per block, all 4 waves share the same span,
// blocks retire cleanly, and the 1024-deep grid (avg span 16.5 iters)
// backfills each CU — 16 waves/CU of mutually-independent waves.
// blockIdx.y = r dispatches longest blocks (r=0, 32 iters) first.
// Per-iter math/staging identical to R3's attn_2ph (proven).
// Row 2047: (r=0,w=3) accumulates Vsum over all 32 V-tiles and writes
// row 2047 = mean(V); (r=31,w=3) skips its s==2047 store (R1-proven, no
// race: only one block writes that row).
// ---------------------------------------------------------------------------
__global__ __launch_bounds__(256, 4) void attn_1ph(
    const unsigned short* __restrict__ qh, const unsigned short* __restrict__ kh,
    const unsigned short* __restrict__ vth, unsigned short* __restrict__ vals) {
  __shared__ unsigned short sm[2 * 8192 + 4096];  // 2 stage sets (K+V) + P = 40KB
  const int tid = threadIdx.x;
  const int lane = tid & 63;
  const int w = tid >> 6;
  const int l15 = lane & 15;
  const int quad = lane >> 4;
  const int bh = blockIdx.x;
  const int r = blockIdx.y;            // row-block 0..31; span = 32-r iters
  const size_t base = (size_t)bh * (Ss * HDd);
  const int b = bh >> 4;
  const int h = bh & 15;
  const int PB = 16384;  // P region base (shorts)
  const int rb = 64 * r + 16 * w;      // this wave's 16 query rows

  // staging offsets (same swizzled slot map as R0/R3)
  const int c0 = w * 128 + lane;
  const int c1 = c0 + 64;
  const int r0 = c0 >> 3, r1 = c1 >> 3;
  const int s0 = ((c0 & 7) ^ (r0 & 7)) * 8;
  const int s1 = ((c1 & 7) ^ (r1 & 7)) * 8;
  const int koff0 = r0 * 64 + s0, koff1 = r1 * 64 + s1;
  const int voff0 = r0 * 2048 + s0, voff1 = r1 * 2048 + s1;
  const int ldsc0 = c0 * 8;
  const int ldsc1 = c1 * 8;

  bfrag vone;
#pragma unroll
  for (int j = 0; j < 8; ++j) vone[j] = (short)0x3F80;  // bf16 1.0

  const bool fixsrc = (r == 0) && (w == 3);   // sees all 32 V tiles
  const bool fixskip = (r == 31) && (w == 3); // nominal owner of row 2047
  ffrag Vsum[4];
#pragma unroll
  for (int dt = 0; dt < 4; ++dt) Vsum[dt] = (ffrag)0.f;

  // Q fragments (Q pre-scaled by 0.125*log2e at gemm_qkv)
  bfrag Qf[2];
#pragma unroll
  for (int ks = 0; ks < 2; ++ks)
    Qf[ks] = *(const bfrag*)(qh + base + (size_t)(rb + l15) * 64 + ks * 32 + quad * 8);

  ffrag O[4], Oe;
#pragma unroll
  for (int dt = 0; dt < 4; ++dt) O[dt] = (ffrag)0.f;
  Oe = (ffrag)0.f;

  int cur = 0, nxt = 8192;  // short offsets of the two stage sets
  {  // prologue: stage tile r into cur
    const unsigned short* kp = kh + base + r * 4096;
    const unsigned short* vp = vth + base + r * 64;
    async_copy16(&sm[cur + ldsc0], kp + koff0);
    async_copy16(&sm[cur + ldsc1], kp + koff1);
    async_copy16(&sm[cur + 4096 + ldsc0], vp + voff0);
    async_copy16(&sm[cur + 4096 + ldsc1], vp + voff1);
  }

  for (int kt = r; kt < 32; ++kt) {
    __syncthreads();  // drains own DMA (vmcnt 0) + seals nxt for overwrite
    if (kt + 1 < 32) {  // prefetch next tile into nxt (covered by compute)
      const unsigned short* kp = kh + base + (kt + 1) * 4096;
      const unsigned short* vp = vth + base + (kt + 1) * 64;
      async_copy16(&sm[nxt + ldsc0], kp + koff0);
      async_copy16(&sm[nxt + ldsc1], kp + koff1);
      async_copy16(&sm[nxt + 4096 + ldsc0], vp + voff0);
      async_copy16(&sm[nxt + 4096 + ldsc1], vp + voff1);
    }

    // ---- S = Q K^T (Q pre-scaled; K single bf16 from LDS)
    ffrag S[4];
#pragma unroll
    for (int nt = 0; nt < 4; ++nt) S[nt] = (ffrag)0.f;
#pragma unroll
    for (int nt = 0; nt < 4; ++nt) {
      const int krow = nt * 16 + l15;
#pragma unroll
      for (int ks = 0; ks < 2; ++ks) {
        const bfrag kbh =
            *(const bfrag*)&sm[cur + krow * 64 + ((ks * 4 + quad) ^ (krow & 7)) * 8];
        S[nt] = __builtin_amdgcn_mfma_f32_16x16x32_bf16(Qf[ks], kbh, S[nt], 0, 0, 0);
      }
    }

    // ---- p = exp2(S [+ CM if masked]); packed bf16 cvt; store to P LDS
    const float CM = -1.442695041e9f;  // -1e9 * log2(e)
    const bool partial = (kt == r);
#pragma unroll
    for (int nt = 0; nt < 4; ++nt) {
      const int key = nt * 16 + l15;
#pragma unroll
      for (int rp = 0; rp < 2; ++rp) {
        float t0 = S[nt][2 * rp];
        float t1 = S[nt][2 * rp + 1];
        if (partial) {
          const int jg = kt * 64 + key;
          const int ig = rb + quad * 4 + 2 * rp;
          if (jg <= ig) t0 += CM;
          if (jg <= ig + 1) t1 += CM;
        }
        float2 pf;
        pf.x = __builtin_amdgcn_exp2f(t0);
        pf.y = __builtin_amdgcn_exp2f(t1);
        const __hip_bfloat162 pb = __float22bfloat162_rn(pf);
        const unsigned short* pbs = (const unsigned short*)&pb;
        const int pr0 = w * 16 + quad * 4 + 2 * rp;
        sm[PB + pr0 * 64 + (((key >> 3) ^ (pr0 & 7)) * 8 + (key & 7))] = pbs[0];
        const int pr1 = pr0 + 1;
        sm[PB + pr1 * 64 + (((key >> 3) ^ (pr1 & 7)) * 8 + (key & 7))] = pbs[1];
      }
    }

    // ---- PV (V single bf16 from LDS) + l via ones-MFMA (+ Vsum, fix wave)
#pragma unroll
    for (int ks = 0; ks < 2; ++ks) {
      const int prow = w * 16 + l15;
      const bfrag pA =
          *(const bfrag*)&sm[PB + prow * 64 + ((ks * 4 + quad) ^ (prow & 7)) * 8];
      Oe = __builtin_amdgcn_mfma_f32_16x16x32_bf16(pA, vone, Oe, 0, 0, 0);
#pragma unroll
      for (int dt = 0; dt < 4; ++dt) {
        const int vrow = dt * 16 + l15;
        const bfrag vbh =
            *(const bfrag*)&sm[cur + 4096 + vrow * 64 + ((ks * 4 + quad) ^ (vrow & 7)) * 8];
        O[dt] = __builtin_amdgcn_mfma_f32_16x16x32_bf16(pA, vbh, O[dt], 0, 0, 0);
        if (fixsrc)
          Vsum[dt] = __builtin_amdgcn_mfma_f32_16x16x32_bf16(vone, vbh, Vsum[dt], 0, 0, 0);
      }
    }
    const int t = cur; cur = nxt; nxt = t;  // swap stage sets
  }

  // ---- epilogue: vals[b][s][h*64+d] single bf16; l = Oe row sum.
#pragma unroll
  for (int rr = 0; rr < 4; ++rr) {
    const float inv = 1.0f / Oe[rr];
    const int s = rb + quad * 4 + rr;
    const size_t rowoff = ((size_t)b * 2048 + s) * 1024 + h * 64;
#pragma unroll
    for (int dt = 0; dt < 4; ++dt) {
      if (fixskip && quad == 3 && rr == 3) continue;  // s==2047: written by fixsrc
      vals[rowoff + dt * 16 + l15] = f2bf(O[dt][rr] * inv);
    }
  }
  if (fixsrc && quad == 3) {  // row 2047 (fully masked -> uniform) = mean(V)
    const size_t rowoff = ((size_t)b * 2048 + 2047) * 1024 + h * 64;
#pragma unroll
    for (int dt = 0; dt < 4; ++dt)
      vals[rowoff + dt * 16 + l15] = f2bf(Vsum[dt][3] * (1.0f / 2048.0f));
  }
}

// ---------------------------------------------------------------------------
// ws (64 MB): qh[0,8) kh[8,16) vth[16,24) vals[24,32)
// wqh[48,54) wql[54,60) woh[60,62) wol[62,64).
// d_out: xh[0,8) (dead after gemm_qkv); gemm_out2 writes final fp32 directly.
// ---------------------------------------------------------------------------
extern "C" void kernel_launch(void* const* d_in, const int* in_sizes, int n_in,
                              void* d_out, int out_size, void* d_ws, size_t ws_size,
                              hipStream_t stream) {
  const float* x    = (const float*)d_in[0];
  const float* Wqkv = (const float*)d_in[1];
  const float* bqkv = (const float*)d_in[2];
  const float* Wout = (const float*)d_in[3];
  const float* bout = (const float*)d_in[4];
  float* out = (float*)d_out;
  char* wsb = (char*)d_ws;

  unsigned short* qhp  = (unsigned short*)d_ws;
  unsigned short* khp  = qhp + 1 * 4194304;
  unsigned short* vthp = qhp + 2 * 4194304;
  unsigned short* vals = qhp + 3 * 4194304;
  unsigned short* wqh  = (unsigned short*)(wsb + (48u << 20));
  unsigned short* wql  = (unsigned short*)(wsb + (54u << 20));
  unsigned short* woh  = (unsigned short*)(wsb + (60u << 20));
  unsigned short* wol  = (unsigned short*)(wsb + (62u << 20));
  unsigned short* xh   = (unsigned short*)d_out;

  dim3 blk(256);
  split_all<<<8192, blk, 0, stream>>>(x, xh, Wqkv, wqh, wql, Wout, woh, wol);
  gemm_qkv<<<dim3(32, 24), blk, 0, stream>>>(xh, wqh, wql, bqkv, qhp, khp, vthp);
  attn_1ph<<<dim3(32, 32), blk, 0, stream>>>(qhp, khp, vthp, vals);
  gemm_out2<<<dim3(32, 16), blk, 0, stream>>>(vals, woh, wol, bout, out);
}

// Round 12
// 202.477 us; speedup vs baseline: 1.0342x; 1.0342x over previous
//
#include <hip/hip_runtime.h>
#include <hip/hip_bf16.h>
#include <math.h>

#define Bb 2
#define Ss 2048
#define Ee 1024
#define Hh 16
#define HDd 64
#define NEG_INF_F -1000000000.0f

typedef __attribute__((ext_vector_type(8))) short bfrag;     // 8 bf16
typedef __attribute__((ext_vector_type(4))) float ffrag;     // 16x16 C/D
typedef __attribute__((ext_vector_type(16))) float ffrag16;  // 32x32 C/D
typedef __attribute__((ext_vector_type(8))) unsigned short us8;

#define C1F 0.1803368801f  /* 0.125 * log2(e) — folded into Q at gemm_qkv */

// ---- bf16 helpers ----------------------------------------------------------
__device__ __forceinline__ unsigned short f2bf(float x) {
  unsigned u = __float_as_uint(x);
  u += 0x7fffu + ((u >> 16) & 1u);
  return (unsigned short)(u >> 16);
}
__device__ __forceinline__ float bf2f(unsigned short h) {
  return __uint_as_float(((unsigned)h) << 16);
}

__device__ __forceinline__ void async_copy16(void* lds, const void* g) {
  __builtin_amdgcn_global_load_lds(
      (const __attribute__((address_space(1))) unsigned int*)g,
      (__attribute__((address_space(3))) unsigned int*)lds, 16, 0, 0);
}

// ---------------------------------------------------------------------------
// Fused split pass: x (4M) -> hi only; Wqkv (3M), Wout (1M) -> hi/lo.
// ---------------------------------------------------------------------------
__global__ __launch_bounds__(256) void split_all(
    const float* __restrict__ x, unsigned short* __restrict__ xh,
    const float* __restrict__ wq, unsigned short* __restrict__ wqh,
    unsigned short* __restrict__ wql,
    const float* __restrict__ wo, unsigned short* __restrict__ woh,
    unsigned short* __restrict__ wol) {
  int bid = blockIdx.x;
  const float* in;
  unsigned short *hi, *lo;
  if (bid < 4096) { in = x; hi = xh; lo = nullptr; }
  else if (bid < 7168) { bid -= 4096; in = wq; hi = wqh; lo = wql; }
  else { bid -= 7168; in = wo; hi = woh; lo = wol; }
  const int idx = (bid * 256 + threadIdx.x) * 4;
  const float4 v = *(const float4*)(in + idx);
  unsigned short h0 = f2bf(v.x), h1 = f2bf(v.y), h2 = f2bf(v.z), h3 = f2bf(v.w);
  ushort4 hv = {h0, h1, h2, h3};
  *(ushort4*)(hi + idx) = hv;
  if (lo) {
    ushort4 lv = {f2bf(v.x - bf2f(h0)), f2bf(v.y - bf2f(h1)),
                  f2bf(v.z - bf2f(h2)), f2bf(v.w - bf2f(h3))};
    *(ushort4*)(lo + idx) = lv;
  }
}

// ---------------------------------------------------------------------------
// LDS slot map (rows of 32 bf16 = 4 x 16B chunks):
// slot(row,q) = (row>>1)*8 + ((((row&1)*4)|q) ^ ((row>>1)&7)).
// ---------------------------------------------------------------------------
__device__ __forceinline__ int gemm_slot(int row, int q) {
  return (row >> 1) * 8 + ((((row & 1) * 4) | q) ^ ((row >> 1) & 7));
}
__device__ __forceinline__ int slot_src_off(int slot, int ld) {
  const int dr = slot >> 3;
  const int idx8 = (slot & 7) ^ (dr & 7);
  const int row = dr * 2 + (idx8 >> 2);
  const int q = idx8 & 3;
  return row * ld + q * 8;
}

// ---------------------------------------------------------------------------
// QKV GEMM, 32x32x16 core: C = xh * (Wh + Wl)^T + bias (2 MFMAs/product).
// 128x128 tile, single-buffered stage->compute loop (R3 form — best measured
// TOTAL config; all pipeline variants R4/R5/R7 within noise or worse on the
// total). Epilogue (all single bf16): Q pre-scaled by C1F -> [bh][s][64];
// K -> [bh][s][64]; V^T -> [bh][d][s].
// ---------------------------------------------------------------------------
__global__ __launch_bounds__(256) void gemm_qkv(
    const unsigned short* __restrict__ Ah,
    const unsigned short* __restrict__ Bh, const unsigned short* __restrict__ Bl,
    const float* __restrict__ bias,
    unsigned short* __restrict__ q_h, unsigned short* __restrict__ k_h,
    unsigned short* __restrict__ vt_h) {
  __shared__ unsigned short sm[3 * 4096];
  const int tid = threadIdx.x;
  const int lane = tid & 63;
  const int w = tid >> 6;
  const int wm = w >> 1;
  const int wn = w & 1;
  const int l31 = lane & 31;
  const int e = lane >> 5;
  const int m0 = blockIdx.x * 128;
  const int n0 = blockIdx.y * 128;

  int coff[2], ldsb[2];
#pragma unroll
  for (int u = 0; u < 2; ++u) {
    const int slot = w * 128 + u * 64 + lane;
    coff[u] = slot_src_off(slot, 1024);
    ldsb[u] = (w * 128 + u * 64) * 8;
  }
  const unsigned short* srcs[3] = {
      Ah + (size_t)m0 * 1024, Bh + (size_t)n0 * 1024, Bl + (size_t)n0 * 1024};

  ffrag16 acc[2][2];
#pragma unroll
  for (int i = 0; i < 2; ++i)
#pragma unroll
    for (int j = 0; j < 2; ++j) acc[i][j] = (ffrag16)0.f;

  int ca[2][2], cb[2][2];
#pragma unroll
  for (int t = 0; t < 2; ++t)
#pragma unroll
    for (int h2 = 0; h2 < 2; ++h2) {
      ca[t][h2] = gemm_slot(wm * 64 + t * 32 + l31, h2 * 2 + e) * 8;
      cb[t][h2] = gemm_slot(wn * 64 + t * 32 + l31, h2 * 2 + e) * 8;
    }

  for (int k0 = 0; k0 < 1024; k0 += 32) {
    __syncthreads();
#pragma unroll
    for (int t = 0; t < 3; ++t)
#pragma unroll
      for (int u = 0; u < 2; ++u)
        async_copy16(&sm[t * 4096 + ldsb[u]], srcs[t] + coff[u] + k0);
    __syncthreads();

    bfrag ah[2][2], bhf[2][2], blf[2][2];
#pragma unroll
    for (int t = 0; t < 2; ++t)
#pragma unroll
      for (int h2 = 0; h2 < 2; ++h2) {
        ah[t][h2] = *(const bfrag*)&sm[0 * 4096 + ca[t][h2]];
        bhf[t][h2] = *(const bfrag*)&sm[1 * 4096 + cb[t][h2]];
        blf[t][h2] = *(const bfrag*)&sm[2 * 4096 + cb[t][h2]];
      }
#pragma unroll
    for (int mt = 0; mt < 2; ++mt)
#pragma unroll
      for (int nt = 0; nt < 2; ++nt)
#pragma unroll
        for (int h2 = 0; h2 < 2; ++h2) {
          acc[mt][nt] = __builtin_amdgcn_mfma_f32_32x32x16_bf16(
              ah[mt][h2], bhf[nt][h2], acc[mt][nt], 0, 0, 0);
          acc[mt][nt] = __builtin_amdgcn_mfma_f32_32x32x16_bf16(
              ah[mt][h2], blf[nt][h2], acc[mt][nt], 0, 0, 0);
        }
  }

#pragma unroll
  for (int nt = 0; nt < 2; ++nt) {
    const int n = n0 + wn * 64 + nt * 32 + l31;
    const float bv = bias[n];
    const int h = n / 192;
    const int c = n - h * 192;
    const int d = c & 63;
#pragma unroll
    for (int mt = 0; mt < 2; ++mt) {
      if (c >= 128) {
#pragma unroll
        for (int g = 0; g < 4; ++g) {
          const int m = m0 + wm * 64 + mt * 32 + g * 8 + e * 4;
          const int bidx = m >> 11;
          const int s = m & 2047;
          ushort4 hv4;
          unsigned short* ph = (unsigned short*)&hv4;
#pragma unroll
          for (int r = 0; r < 4; ++r)
            ph[r] = f2bf(acc[mt][nt][g * 4 + r] + bv);
          const size_t off =
              (size_t)(bidx * 16 + h) * (64 * 2048) + (size_t)d * 2048 + s;
          *(ushort4*)(vt_h + off) = hv4;
        }
      } else {
        const float scale = (c < 64) ? C1F : 1.0f;
        unsigned short* dh = (c < 64) ? q_h : k_h;
#pragma unroll
        for (int g = 0; g < 4; ++g)
#pragma unroll
          for (int r = 0; r < 4; ++r) {
            const int m = m0 + wm * 64 + mt * 32 + g * 8 + e * 4 + r;
            const int bidx = m >> 11;
            const int s = m & 2047;
            const size_t off =
                (size_t)(bidx * 16 + h) * (2048 * 64) + (size_t)s * 64 + d;
            dh[off] = f2bf((acc[mt][nt][g * 4 + r] + bv) * scale);
          }
      }
    }
  }
}

// ---------------------------------------------------------------------------
// Out-proj GEMM: A = vals single bf16, B = Wout hi/lo (2 MFMAs/product).
// 128x64 tile, 512 blocks. SINGLE-buffered (measured best for this kernel).
// Writes fp32+bias directly to out.
// ---------------------------------------------------------------------------
__global__ __launch_bounds__(256) void gemm_out2(
    const unsigned short* __restrict__ A,
    const unsigned short* __restrict__ Bh, const unsigned short* __restrict__ Bl,
    const float* __restrict__ bias, float* __restrict__ out) {
  __shared__ unsigned short sm[8192];
  const int tid = threadIdx.x;
  const int lane = tid & 63;
  const int w = tid >> 6;
  const int wm = w >> 1;
  const int wn = w & 1;
  const int l31 = lane & 31;
  const int e = lane >> 5;
  const int m0 = blockIdx.x * 128;
  const int n0 = blockIdx.y * 64;

  int acoff[2], aldsb[2];
#pragma unroll
  for (int u = 0; u < 2; ++u) {
    const int slot = w * 128 + u * 64 + lane;
    acoff[u] = slot_src_off(slot, 1024);
    aldsb[u] = (w * 128 + u * 64) * 8;
  }
  const int bslot = w * 64 + lane;
  const int bcoff = slot_src_off(bslot, 1024);
  const int bldsb = bslot * 8;

  const unsigned short* Ap  = A + (size_t)m0 * 1024;
  const unsigned short* Bph = Bh + (size_t)n0 * 1024;
  const unsigned short* Bpl = Bl + (size_t)n0 * 1024;

  ffrag16 acc[2];
  acc[0] = (ffrag16)0.f;
  acc[1] = (ffrag16)0.f;

  int ca[2][2], cb[2];
#pragma unroll
  for (int t = 0; t < 2; ++t)
#pragma unroll
    for (int h2 = 0; h2 < 2; ++h2)
      ca[t][h2] = gemm_slot(wm * 64 + t * 32 + l31, h2 * 2 + e) * 8;
#pragma unroll
  for (int h2 = 0; h2 < 2; ++h2)
    cb[h2] = gemm_slot(wn * 32 + l31, h2 * 2 + e) * 8;

  for (int k0 = 0; k0 < 1024; k0 += 32) {
    __syncthreads();
#pragma unroll
    for (int u = 0; u < 2; ++u)
      async_copy16(&sm[0 + aldsb[u]], Ap + acoff[u] + k0);
    async_copy16(&sm[4096 + bldsb], Bph + bcoff + k0);
    async_copy16(&sm[6144 + bldsb], Bpl + bcoff + k0);
    __syncthreads();

    bfrag ah[2][2], bhf[2], blf[2];
#pragma unroll
    for (int t = 0; t < 2; ++t)
#pragma unroll
      for (int h2 = 0; h2 < 2; ++h2)
        ah[t][h2] = *(const bfrag*)&sm[0 + ca[t][h2]];
#pragma unroll
    for (int h2 = 0; h2 < 2; ++h2) {
      bhf[h2] = *(const bfrag*)&sm[4096 + cb[h2]];
      blf[h2] = *(const bfrag*)&sm[6144 + cb[h2]];
    }
#pragma unroll
    for (int mt = 0; mt < 2; ++mt)
#pragma unroll
      for (int h2 = 0; h2 < 2; ++h2) {
        acc[mt] = __builtin_amdgcn_mfma_f32_32x32x16_bf16(
            ah[mt][h2], bhf[h2], acc[mt], 0, 0, 0);
        acc[mt] = __builtin_amdgcn_mfma_f32_32x32x16_bf16(
            ah[mt][h2], blf[h2], acc[mt], 0, 0, 0);
      }
  }

  const int n = n0 + wn * 32 + l31;
  const float bv = bias[n];
#pragma unroll
  for (int mt = 0; mt < 2; ++mt)
#pragma unroll
    for (int g = 0; g < 4; ++g)
#pragma unroll
      for (int r = 0; r < 4; ++r) {
        const int m = m0 + wm * 64 + mt * 32 + g * 8 + e * 4 + r;
        out[(size_t)m * 1024 + n] = acc[mt][g * 4 + r] + bv;
      }
}

// ---------------------------------------------------------------------------
// Two-phase balanced flash attention, double-buffered LDS staging (R3 form —
// best measured across R3/R8/R10 variants). Each block runs row-block y
// (span 32-y) then 31-y (span y+1): uniform 33-iter span; 40KB LDS.
// Row 2047 fixup on (y=0,w=3): Vsum in phase A, owns row 2047 in phase B.
// ---------------------------------------------------------------------------
__global__ __launch_bounds__(256, 4) void attn_2ph(
    const unsigned short* __restrict__ qh, const unsigned short* __restrict__ kh,
    const unsigned short* __restrict__ vth, unsigned short* __restrict__ vals) {
  __shared__ unsigned short sm[2 * 8192 + 4096];  // 2 stage sets (K+V) + P = 40KB
  const int tid = threadIdx.x;
  const int lane = tid & 63;
  const int w = tid >> 6;
  const int l15 = lane & 15;
  const int quad = lane >> 4;
  const int bh = blockIdx.x;
  const int y = blockIdx.y;
  const size_t base = (size_t)bh * (Ss * HDd);
  const int b = bh >> 4;
  const int h = bh & 15;
  const int PB = 16384;  // P region base (shorts)

  // staging offsets (same swizzled slot map as R0)
  const int c0 = w * 128 + lane;
  const int c1 = c0 + 64;
  const int r0 = c0 >> 3, r1 = c1 >> 3;
  const int s0 = ((c0 & 7) ^ (r0 & 7)) * 8;
  const int s1 = ((c1 & 7) ^ (r1 & 7)) * 8;
  const int koff0 = r0 * 64 + s0, koff1 = r1 * 64 + s1;
  const int voff0 = r0 * 2048 + s0, voff1 = r1 * 2048 + s1;
  const int ldsc0 = c0 * 8;
  const int ldsc1 = c1 * 8;

  bfrag vone;
#pragma unroll
  for (int j = 0; j < 8; ++j) vone[j] = (short)0x3F80;  // bf16 1.0

  const bool fixw = (y == 0) && (w == 3);  // phase A sees all kt; phase B owns row 2047
  ffrag Vsum[4];
#pragma unroll
  for (int dt = 0; dt < 4; ++dt) Vsum[dt] = (ffrag)0.f;

  for (int ph = 0; ph < 2; ++ph) {
    const int ybk = ph ? (31 - y) : y;
    const int rb = 64 * ybk + 16 * w;  // this wave's 16 query rows

    // Q fragments (Q pre-scaled by 0.125*log2e at gemm_qkv)
    bfrag Qf[2];
#pragma unroll
    for (int ks = 0; ks < 2; ++ks)
      Qf[ks] = *(const bfrag*)(qh + base + (size_t)(rb + l15) * 64 + ks * 32 + quad * 8);

    ffrag O[4], Oe;
#pragma unroll
    for (int dt = 0; dt < 4; ++dt) O[dt] = (ffrag)0.f;
    Oe = (ffrag)0.f;

    int cur = 0, nxt = 8192;  // short offsets of the two stage sets
    {  // prologue: stage tile ybk into cur
      const unsigned short* kp = kh + base + ybk * 4096;
      const unsigned short* vp = vth + base + ybk * 64;
      async_copy16(&sm[cur + ldsc0], kp + koff0);
      async_copy16(&sm[cur + ldsc1], kp + koff1);
      async_copy16(&sm[cur + 4096 + ldsc0], vp + voff0);
      async_copy16(&sm[cur + 4096 + ldsc1], vp + voff1);
    }

    for (int kt = ybk; kt < 32; ++kt) {
      __syncthreads();  // drains own DMA (vmcnt 0) + seals nxt for overwrite
      if (kt + 1 < 32) {  // prefetch next tile into nxt (covered by compute)
        const unsigned short* kp = kh + base + (kt + 1) * 4096;
        const unsigned short* vp = vth + base + (kt + 1) * 64;
        async_copy16(&sm[nxt + ldsc0], kp + koff0);
        async_copy16(&sm[nxt + ldsc1], kp + koff1);
        async_copy16(&sm[nxt + 4096 + ldsc0], vp + voff0);
        async_copy16(&sm[nxt + 4096 + ldsc1], vp + voff1);
      }

      // ---- S = Q K^T (Q pre-scaled; K single bf16 from LDS)
      ffrag S[4];
#pragma unroll
      for (int nt = 0; nt < 4; ++nt) S[nt] = (ffrag)0.f;
#pragma unroll
      for (int nt = 0; nt < 4; ++nt) {
        const int krow = nt * 16 + l15;
#pragma unroll
        for (int ks = 0; ks < 2; ++ks) {
          const bfrag kbh =
              *(const bfrag*)&sm[cur + krow * 64 + ((ks * 4 + quad) ^ (krow & 7)) * 8];
          S[nt] = __builtin_amdgcn_mfma_f32_16x16x32_bf16(Qf[ks], kbh, S[nt], 0, 0, 0);
        }
      }

      // ---- p = exp2(S [+ CM if masked]); packed bf16 cvt; store to P LDS
      const float CM = -1.442695041e9f;  // -1e9 * log2(e)
      const bool partial = (kt == ybk);
#pragma unroll
      for (int nt = 0; nt < 4; ++nt) {
        const int key = nt * 16 + l15;
#pragma unroll
        for (int rp = 0; rp < 2; ++rp) {
          float t0 = S[nt][2 * rp];
          float t1 = S[nt][2 * rp + 1];
          if (partial) {
            const int jg = kt * 64 + key;
            const int ig = rb + quad * 4 + 2 * rp;
            if (jg <= ig) t0 += CM;
            if (jg <= ig + 1) t1 += CM;
          }
          float2 pf;
          pf.x = __builtin_amdgcn_exp2f(t0);
          pf.y = __builtin_amdgcn_exp2f(t1);
          const __hip_bfloat162 pb = __float22bfloat162_rn(pf);
          const unsigned short* pbs = (const unsigned short*)&pb;
          const int pr0 = w * 16 + quad * 4 + 2 * rp;
          sm[PB + pr0 * 64 + (((key >> 3) ^ (pr0 & 7)) * 8 + (key & 7))] = pbs[0];
          const int pr1 = pr0 + 1;
          sm[PB + pr1 * 64 + (((key >> 3) ^ (pr1 & 7)) * 8 + (key & 7))] = pbs[1];
        }
      }

      // ---- PV (V single bf16 from LDS) + l via ones-MFMA (+ Vsum, fix wave)
#pragma unroll
      for (int ks = 0; ks < 2; ++ks) {
        const int prow = w * 16 + l15;
        const bfrag pA =
            *(const bfrag*)&sm[PB + prow * 64 + ((ks * 4 + quad) ^ (prow & 7)) * 8];
        Oe = __builtin_amdgcn_mfma_f32_16x16x32_bf16(pA, vone, Oe, 0, 0, 0);
#pragma unroll
        for (int dt = 0; dt < 4; ++dt) {
          const int vrow = dt * 16 + l15;
          const bfrag vbh =
              *(const bfrag*)&sm[cur + 4096 + vrow * 64 + ((ks * 4 + quad) ^ (vrow & 7)) * 8];
          O[dt] = __builtin_amdgcn_mfma_f32_16x16x32_bf16(pA, vbh, O[dt], 0, 0, 0);
          if (fixw && ph == 0)
            Vsum[dt] = __builtin_amdgcn_mfma_f32_16x16x32_bf16(vone, vbh, Vsum[dt], 0, 0, 0);
        }
      }
      const int t = cur; cur = nxt; nxt = t;  // swap stage sets
    }

    // ---- epilogue: vals[b][s][h*64+d] single bf16; l = Oe row sum.
    // Row 2047 (fully masked -> exactly uniform) = mean(V), from Vsum (phase B).
#pragma unroll
    for (int r = 0; r < 4; ++r) {
      const float inv = 1.0f / Oe[r];
      const int s = rb + quad * 4 + r;
      const size_t rowoff = ((size_t)b * 2048 + s) * 1024 + h * 64;
#pragma unroll
      for (int dt = 0; dt < 4; ++dt) {
        float val = O[dt][r] * inv;
        if (fixw && ph == 1 && quad == 3 && r == 3)  // s == 2047
          val = Vsum[dt][3] * (1.0f / 2048.0f);
        vals[rowoff + dt * 16 + l15] = f2bf(val);
      }
    }
    __syncthreads();  // seal all stage reads before next phase's prologue DMA
  }
}

// ---------------------------------------------------------------------------
// ws (64 MB): qh[0,8) kh[8,16) vth[16,24) vals[24,32)
// wqh[48,54) wql[54,60) woh[60,62) wol[62,64).
// d_out: xh[0,8) (dead after gemm_qkv); gemm_out2 writes final fp32 directly.
// ---------------------------------------------------------------------------
extern "C" void kernel_launch(void* const* d_in, const int* in_sizes, int n_in,
                              void* d_out, int out_size, void* d_ws, size_t ws_size,
                              hipStream_t stream) {
  const float* x    = (const float*)d_in[0];
  const float* Wqkv = (const float*)d_in[1];
  const float* bqkv = (const float*)d_in[2];
  const float* Wout = (const float*)d_in[3];
  const float* bout = (const float*)d_in[4];
  float* out = (float*)d_out;
  char* wsb = (char*)d_ws;

  unsigned short* qhp  = (unsigned short*)d_ws;
  unsigned short* khp  = qhp + 1 * 4194304;
  unsigned short* vthp = qhp + 2 * 4194304;
  unsigned short* vals = qhp + 3 * 4194304;
  unsigned short* wqh  = (unsigned short*)(wsb + (48u << 20));
  unsigned short* wql  = (unsigned short*)(wsb + (54u << 20));
  unsigned short* woh  = (unsigned short*)(wsb + (60u << 20));
  unsigned short* wol  = (unsigned short*)(wsb + (62u << 20));
  unsigned short* xh   = (unsigned short*)d_out;

  dim3 blk(256);
  split_all<<<8192, blk, 0, stream>>>(x, xh, Wqkv, wqh, wql, Wout, woh, wol);
  gemm_qkv<<<dim3(32, 24), blk, 0, stream>>>(xh, wqh, wql, bqkv, qhp, khp, vthp);
  attn_2ph<<<dim3(32, 16), blk, 0, stream>>>(qhp, khp, vthp, vals);
  gemm_out2<<<dim3(32, 16), blk, 0, stream>>>(vals, woh, wol, bout, out);
}

// Round 13
// 200.509 us; speedup vs baseline: 1.0443x; 1.0098x over previous
//
#include <hip/hip_runtime.h>
#include <hip/hip_bf16.h>
#include <math.h>

#define Bb 2
#define Ss 2048
#define Ee 1024
#define Hh 16
#define HDd 64
#define NEG_INF_F -1000000000.0f

typedef __attribute__((ext_vector_type(8))) short bfrag;     // 8 bf16
typedef __attribute__((ext_vector_type(4))) float ffrag;     // 16x16 C/D
typedef __attribute__((ext_vector_type(16))) float ffrag16;  // 32x32 C/D
typedef __attribute__((ext_vector_type(8))) unsigned short us8;

#define C1F 0.1803368801f  /* 0.125 * log2(e) — folded into Q at gemm_qkv */

// ---- bf16 helpers ----------------------------------------------------------
__device__ __forceinline__ unsigned short f2bf(float x) {
  unsigned u = __float_as_uint(x);
  u += 0x7fffu + ((u >> 16) & 1u);
  return (unsigned short)(u >> 16);
}
__device__ __forceinline__ float bf2f(unsigned short h) {
  return __uint_as_float(((unsigned)h) << 16);
}

__device__ __forceinline__ void async_copy16(void* lds, const void* g) {
  __builtin_amdgcn_global_load_lds(
      (const __attribute__((address_space(1))) unsigned int*)g,
      (__attribute__((address_space(3))) unsigned int*)lds, 16, 0, 0);
}

// ---------------------------------------------------------------------------
// Fused split pass: x (4M) -> hi only; Wqkv (3M), Wout (1M) -> hi/lo.
// ---------------------------------------------------------------------------
__global__ __launch_bounds__(256) void split_all(
    const float* __restrict__ x, unsigned short* __restrict__ xh,
    const float* __restrict__ wq, unsigned short* __restrict__ wqh,
    unsigned short* __restrict__ wql,
    const float* __restrict__ wo, unsigned short* __restrict__ woh,
    unsigned short* __restrict__ wol) {
  int bid = blockIdx.x;
  const float* in;
  unsigned short *hi, *lo;
  if (bid < 4096) { in = x; hi = xh; lo = nullptr; }
  else if (bid < 7168) { bid -= 4096; in = wq; hi = wqh; lo = wql; }
  else { bid -= 7168; in = wo; hi = woh; lo = wol; }
  const int idx = (bid * 256 + threadIdx.x) * 4;
  const float4 v = *(const float4*)(in + idx);
  unsigned short h0 = f2bf(v.x), h1 = f2bf(v.y), h2 = f2bf(v.z), h3 = f2bf(v.w);
  ushort4 hv = {h0, h1, h2, h3};
  *(ushort4*)(hi + idx) = hv;
  if (lo) {
    ushort4 lv = {f2bf(v.x - bf2f(h0)), f2bf(v.y - bf2f(h1)),
                  f2bf(v.z - bf2f(h2)), f2bf(v.w - bf2f(h3))};
    *(ushort4*)(lo + idx) = lv;
  }
}

// ---------------------------------------------------------------------------
// LDS slot map (rows of 32 bf16 = 4 x 16B chunks):
// slot(row,q) = (row>>1)*8 + ((((row&1)*4)|q) ^ ((row>>1)&7)).
// ---------------------------------------------------------------------------
__device__ __forceinline__ int gemm_slot(int row, int q) {
  return (row >> 1) * 8 + ((((row & 1) * 4) | q) ^ ((row >> 1) & 7));
}
__device__ __forceinline__ int slot_src_off(int slot, int ld) {
  const int dr = slot >> 3;
  const int idx8 = (slot & 7) ^ (dr & 7);
  const int row = dr * 2 + (idx8 >> 2);
  const int q = idx8 & 3;
  return row * ld + q * 8;
}

// ---------------------------------------------------------------------------
// QKV GEMM, 32x32x16 core: C = xh * (Wh + Wl)^T + bias (2 MFMAs/product).
// 128x128 tile, BK=64 single-buffered (R13): 16 K-iterations of
// {sync; stage 12 DMAs (two 32-col sub-tiles per matrix); sync; per
// sub-tile: read 12 frags + 16 MFMAs}. Halves the exposed DMA-drain count
// vs BK=32 (16 vs 32 barriers-with-drain) while keeping LDS at 48KB ->
// 3 blocks/CU (grid 768 = 3/CU) and register peak flat (frags read per
// sub-tile, not batched — avoids R2's spill pathology).
// Epilogue (all single bf16): Q pre-scaled by C1F -> [bh][s][64];
// K -> [bh][s][64]; V^T -> [bh][d][s].
// ---------------------------------------------------------------------------
__global__ __launch_bounds__(256) void gemm_qkv(
    const unsigned short* __restrict__ Ah,
    const unsigned short* __restrict__ Bh, const unsigned short* __restrict__ Bl,
    const float* __restrict__ bias,
    unsigned short* __restrict__ q_h, unsigned short* __restrict__ k_h,
    unsigned short* __restrict__ vt_h) {
  __shared__ unsigned short sm[3 * 8192];  // 3 matrices x (2 x 32-col sub-tile) = 48KB
  const int tid = threadIdx.x;
  const int lane = tid & 63;
  const int w = tid >> 6;
  const int wm = w >> 1;
  const int wn = w & 1;
  const int l31 = lane & 31;
  const int e = lane >> 5;
  const int m0 = blockIdx.x * 128;
  const int n0 = blockIdx.y * 128;

  int coff[2], ldsb[2];
#pragma unroll
  for (int u = 0; u < 2; ++u) {
    const int slot = w * 128 + u * 64 + lane;
    coff[u] = slot_src_off(slot, 1024);
    ldsb[u] = (w * 128 + u * 64) * 8;
  }
  const unsigned short* srcs[3] = {
      Ah + (size_t)m0 * 1024, Bh + (size_t)n0 * 1024, Bl + (size_t)n0 * 1024};

  ffrag16 acc[2][2];
#pragma unroll
  for (int i = 0; i < 2; ++i)
#pragma unroll
    for (int j = 0; j < 2; ++j) acc[i][j] = (ffrag16)0.f;

  int ca[2][2], cb[2][2];
#pragma unroll
  for (int t = 0; t < 2; ++t)
#pragma unroll
    for (int h2 = 0; h2 < 2; ++h2) {
      ca[t][h2] = gemm_slot(wm * 64 + t * 32 + l31, h2 * 2 + e) * 8;
      cb[t][h2] = gemm_slot(wn * 64 + t * 32 + l31, h2 * 2 + e) * 8;
    }

  for (int k0 = 0; k0 < 1024; k0 += 64) {
    __syncthreads();
#pragma unroll
    for (int t = 0; t < 3; ++t)
#pragma unroll
      for (int s = 0; s < 2; ++s)
#pragma unroll
        for (int u = 0; u < 2; ++u)
          async_copy16(&sm[t * 8192 + s * 4096 + ldsb[u]],
                       srcs[t] + coff[u] + k0 + s * 32);
    __syncthreads();

#pragma unroll
    for (int s = 0; s < 2; ++s) {
      const int sb = s * 4096;
      bfrag ah[2][2], bhf[2][2], blf[2][2];
#pragma unroll
      for (int t = 0; t < 2; ++t)
#pragma unroll
        for (int h2 = 0; h2 < 2; ++h2) {
          ah[t][h2] = *(const bfrag*)&sm[0 * 8192 + sb + ca[t][h2]];
          bhf[t][h2] = *(const bfrag*)&sm[1 * 8192 + sb + cb[t][h2]];
          blf[t][h2] = *(const bfrag*)&sm[2 * 8192 + sb + cb[t][h2]];
        }
#pragma unroll
      for (int mt = 0; mt < 2; ++mt)
#pragma unroll
        for (int nt = 0; nt < 2; ++nt)
#pragma unroll
          for (int h2 = 0; h2 < 2; ++h2) {
            acc[mt][nt] = __builtin_amdgcn_mfma_f32_32x32x16_bf16(
                ah[mt][h2], bhf[nt][h2], acc[mt][nt], 0, 0, 0);
            acc[mt][nt] = __builtin_amdgcn_mfma_f32_32x32x16_bf16(
                ah[mt][h2], blf[nt][h2], acc[mt][nt], 0, 0, 0);
          }
    }
  }

#pragma unroll
  for (int nt = 0; nt < 2; ++nt) {
    const int n = n0 + wn * 64 + nt * 32 + l31;
    const float bv = bias[n];
    const int h = n / 192;
    const int c = n - h * 192;
    const int d = c & 63;
#pragma unroll
    for (int mt = 0; mt < 2; ++mt) {
      if (c >= 128) {
#pragma unroll
        for (int g = 0; g < 4; ++g) {
          const int m = m0 + wm * 64 + mt * 32 + g * 8 + e * 4;
          const int bidx = m >> 11;
          const int s = m & 2047;
          ushort4 hv4;
          unsigned short* ph = (unsigned short*)&hv4;
#pragma unroll
          for (int r = 0; r < 4; ++r)
            ph[r] = f2bf(acc[mt][nt][g * 4 + r] + bv);
          const size_t off =
              (size_t)(bidx * 16 + h) * (64 * 2048) + (size_t)d * 2048 + s;
          *(ushort4*)(vt_h + off) = hv4;
        }
      } else {
        const float scale = (c < 64) ? C1F : 1.0f;
        unsigned short* dh = (c < 64) ? q_h : k_h;
#pragma unroll
        for (int g = 0; g < 4; ++g)
#pragma unroll
          for (int r = 0; r < 4; ++r) {
            const int m = m0 + wm * 64 + mt * 32 + g * 8 + e * 4 + r;
            const int bidx = m >> 11;
            const int s = m & 2047;
            const size_t off =
                (size_t)(bidx * 16 + h) * (2048 * 64) + (size_t)s * 64 + d;
            dh[off] = f2bf((acc[mt][nt][g * 4 + r] + bv) * scale);
          }
      }
    }
  }
}

// ---------------------------------------------------------------------------
// Out-proj GEMM: A = vals single bf16, B = Wout hi/lo (2 MFMAs/product).
// 128x64 tile, 512 blocks. SINGLE-buffered (measured best for this kernel).
// Writes fp32+bias directly to out.
// ---------------------------------------------------------------------------
__global__ __launch_bounds__(256) void gemm_out2(
    const unsigned short* __restrict__ A,
    const unsigned short* __restrict__ Bh, const unsigned short* __restrict__ Bl,
    const float* __restrict__ bias, float* __restrict__ out) {
  __shared__ unsigned short sm[8192];
  const int tid = threadIdx.x;
  const int lane = tid & 63;
  const int w = tid >> 6;
  const int wm = w >> 1;
  const int wn = w & 1;
  const int l31 = lane & 31;
  const int e = lane >> 5;
  const int m0 = blockIdx.x * 128;
  const int n0 = blockIdx.y * 64;

  int acoff[2], aldsb[2];
#pragma unroll
  for (int u = 0; u < 2; ++u) {
    const int slot = w * 128 + u * 64 + lane;
    acoff[u] = slot_src_off(slot, 1024);
    aldsb[u] = (w * 128 + u * 64) * 8;
  }
  const int bslot = w * 64 + lane;
  const int bcoff = slot_src_off(bslot, 1024);
  const int bldsb = bslot * 8;

  const unsigned short* Ap  = A + (size_t)m0 * 1024;
  const unsigned short* Bph = Bh + (size_t)n0 * 1024;
  const unsigned short* Bpl = Bl + (size_t)n0 * 1024;

  ffrag16 acc[2];
  acc[0] = (ffrag16)0.f;
  acc[1] = (ffrag16)0.f;

  int ca[2][2], cb[2];
#pragma unroll
  for (int t = 0; t < 2; ++t)
#pragma unroll
    for (int h2 = 0; h2 < 2; ++h2)
      ca[t][h2] = gemm_slot(wm * 64 + t * 32 + l31, h2 * 2 + e) * 8;
#pragma unroll
  for (int h2 = 0; h2 < 2; ++h2)
    cb[h2] = gemm_slot(wn * 32 + l31, h2 * 2 + e) * 8;

  for (int k0 = 0; k0 < 1024; k0 += 32) {
    __syncthreads();
#pragma unroll
    for (int u = 0; u < 2; ++u)
      async_copy16(&sm[0 + aldsb[u]], Ap + acoff[u] + k0);
    async_copy16(&sm[4096 + bldsb], Bph + bcoff + k0);
    async_copy16(&sm[6144 + bldsb], Bpl + bcoff + k0);
    __syncthreads();

    bfrag ah[2][2], bhf[2], blf[2];
#pragma unroll
    for (int t = 0; t < 2; ++t)
#pragma unroll
      for (int h2 = 0; h2 < 2; ++h2)
        ah[t][h2] = *(const bfrag*)&sm[0 + ca[t][h2]];
#pragma unroll
    for (int h2 = 0; h2 < 2; ++h2) {
      bhf[h2] = *(const bfrag*)&sm[4096 + cb[h2]];
      blf[h2] = *(const bfrag*)&sm[6144 + cb[h2]];
    }
#pragma unroll
    for (int mt = 0; mt < 2; ++mt)
#pragma unroll
      for (int h2 = 0; h2 < 2; ++h2) {
        acc[mt] = __builtin_amdgcn_mfma_f32_32x32x16_bf16(
            ah[mt][h2], bhf[h2], acc[mt], 0, 0, 0);
        acc[mt] = __builtin_amdgcn_mfma_f32_32x32x16_bf16(
            ah[mt][h2], blf[h2], acc[mt], 0, 0, 0);
      }
  }

  const int n = n0 + wn * 32 + l31;
  const float bv = bias[n];
#pragma unroll
  for (int mt = 0; mt < 2; ++mt)
#pragma unroll
    for (int g = 0; g < 4; ++g)
#pragma unroll
      for (int r = 0; r < 4; ++r) {
        const int m = m0 + wm * 64 + mt * 32 + g * 8 + e * 4 + r;
        out[(size_t)m * 1024 + n] = acc[mt][g * 4 + r] + bv;
      }
}

// ---------------------------------------------------------------------------
// Two-phase balanced flash attention, double-buffered LDS staging (R3 form —
// best measured across R3/R8/R10 variants). Each block runs row-block y
// (span 32-y) then 31-y (span y+1): uniform 33-iter span; 40KB LDS.
// Row 2047 fixup on (y=0,w=3): Vsum in phase A, owns row 2047 in phase B.
// ---------------------------------------------------------------------------
__global__ __launch_bounds__(256, 4) void attn_2ph(
    const unsigned short* __restrict__ qh, const unsigned short* __restrict__ kh,
    const unsigned short* __restrict__ vth, unsigned short* __restrict__ vals) {
  __shared__ unsigned short sm[2 * 8192 + 4096];  // 2 stage sets (K+V) + P = 40KB
  const int tid = threadIdx.x;
  const int lane = tid & 63;
  const int w = tid >> 6;
  const int l15 = lane & 15;
  const int quad = lane >> 4;
  const int bh = blockIdx.x;
  const int y = blockIdx.y;
  const size_t base = (size_t)bh * (Ss * HDd);
  const int b = bh >> 4;
  const int h = bh & 15;
  const int PB = 16384;  // P region base (shorts)

  // staging offsets (same swizzled slot map as R0)
  const int c0 = w * 128 + lane;
  const int c1 = c0 + 64;
  const int r0 = c0 >> 3, r1 = c1 >> 3;
  const int s0 = ((c0 & 7) ^ (r0 & 7)) * 8;
  const int s1 = ((c1 & 7) ^ (r1 & 7)) * 8;
  const int koff0 = r0 * 64 + s0, koff1 = r1 * 64 + s1;
  const int voff0 = r0 * 2048 + s0, voff1 = r1 * 2048 + s1;
  const int ldsc0 = c0 * 8;
  const int ldsc1 = c1 * 8;

  bfrag vone;
#pragma unroll
  for (int j = 0; j < 8; ++j) vone[j] = (short)0x3F80;  // bf16 1.0

  const bool fixw = (y == 0) && (w == 3);  // phase A sees all kt; phase B owns row 2047
  ffrag Vsum[4];
#pragma unroll
  for (int dt = 0; dt < 4; ++dt) Vsum[dt] = (ffrag)0.f;

  for (int ph = 0; ph < 2; ++ph) {
    const int ybk = ph ? (31 - y) : y;
    const int rb = 64 * ybk + 16 * w;  // this wave's 16 query rows

    // Q fragments (Q pre-scaled by 0.125*log2e at gemm_qkv)
    bfrag Qf[2];
#pragma unroll
    for (int ks = 0; ks < 2; ++ks)
      Qf[ks] = *(const bfrag*)(qh + base + (size_t)(rb + l15) * 64 + ks * 32 + quad * 8);

    ffrag O[4], Oe;
#pragma unroll
    for (int dt = 0; dt < 4; ++dt) O[dt] = (ffrag)0.f;
    Oe = (ffrag)0.f;

    int cur = 0, nxt = 8192;  // short offsets of the two stage sets
    {  // prologue: stage tile ybk into cur
      const unsigned short* kp = kh + base + ybk * 4096;
      const unsigned short* vp = vth + base + ybk * 64;
      async_copy16(&sm[cur + ldsc0], kp + koff0);
      async_copy16(&sm[cur + ldsc1], kp + koff1);
      async_copy16(&sm[cur + 4096 + ldsc0], vp + voff0);
      async_copy16(&sm[cur + 4096 + ldsc1], vp + voff1);
    }

    for (int kt = ybk; kt < 32; ++kt) {
      __syncthreads();  // drains own DMA (vmcnt 0) + seals nxt for overwrite
      if (kt + 1 < 32) {  // prefetch next tile into nxt (covered by compute)
        const unsigned short* kp = kh + base + (kt + 1) * 4096;
        const unsigned short* vp = vth + base + (kt + 1) * 64;
        async_copy16(&sm[nxt + ldsc0], kp + koff0);
        async_copy16(&sm[nxt + ldsc1], kp + koff1);
        async_copy16(&sm[nxt + 4096 + ldsc0], vp + voff0);
        async_copy16(&sm[nxt + 4096 + ldsc1], vp + voff1);
      }

      // ---- S = Q K^T (Q pre-scaled; K single bf16 from LDS)
      ffrag S[4];
#pragma unroll
      for (int nt = 0; nt < 4; ++nt) S[nt] = (ffrag)0.f;
#pragma unroll
      for (int nt = 0; nt < 4; ++nt) {
        const int krow = nt * 16 + l15;
#pragma unroll
        for (int ks = 0; ks < 2; ++ks) {
          const bfrag kbh =
              *(const bfrag*)&sm[cur + krow * 64 + ((ks * 4 + quad) ^ (krow & 7)) * 8];
          S[nt] = __builtin_amdgcn_mfma_f32_16x16x32_bf16(Qf[ks], kbh, S[nt], 0, 0, 0);
        }
      }

      // ---- p = exp2(S [+ CM if masked]); packed bf16 cvt; store to P LDS
      const float CM = -1.442695041e9f;  // -1e9 * log2(e)
      const bool partial = (kt == ybk);
#pragma unroll
      for (int nt = 0; nt < 4; ++nt) {
        const int key = nt * 16 + l15;
#pragma unroll
        for (int rp = 0; rp < 2; ++rp) {
          float t0 = S[nt][2 * rp];
          float t1 = S[nt][2 * rp + 1];
          if (partial) {
            const int jg = kt * 64 + key;
            const int ig = rb + quad * 4 + 2 * rp;
            if (jg <= ig) t0 += CM;
            if (jg <= ig + 1) t1 += CM;
          }
          float2 pf;
          pf.x = __builtin_amdgcn_exp2f(t0);
          pf.y = __builtin_amdgcn_exp2f(t1);
          const __hip_bfloat162 pb = __float22bfloat162_rn(pf);
          const unsigned short* pbs = (const unsigned short*)&pb;
          const int pr0 = w * 16 + quad * 4 + 2 * rp;
          sm[PB + pr0 * 64 + (((key >> 3) ^ (pr0 & 7)) * 8 + (key & 7))] = pbs[0];
          const int pr1 = pr0 + 1;
          sm[PB + pr1 * 64 + (((key >> 3) ^ (pr1 & 7)) * 8 + (key & 7))] = pbs[1];
        }
      }

      // ---- PV (V single bf16 from LDS) + l via ones-MFMA (+ Vsum, fix wave)
#pragma unroll
      for (int ks = 0; ks < 2; ++ks) {
        const int prow = w * 16 + l15;
        const bfrag pA =
            *(const bfrag*)&sm[PB + prow * 64 + ((ks * 4 + quad) ^ (prow & 7)) * 8];
        Oe = __builtin_amdgcn_mfma_f32_16x16x32_bf16(pA, vone, Oe, 0, 0, 0);
#pragma unroll
        for (int dt = 0; dt < 4; ++dt) {
          const int vrow = dt * 16 + l15;
          const bfrag vbh =
              *(const bfrag*)&sm[cur + 4096 + vrow * 64 + ((ks * 4 + quad) ^ (vrow & 7)) * 8];
          O[dt] = __builtin_amdgcn_mfma_f32_16x16x32_bf16(pA, vbh, O[dt], 0, 0, 0);
          if (fixw && ph == 0)
            Vsum[dt] = __builtin_amdgcn_mfma_f32_16x16x32_bf16(vone, vbh, Vsum[dt], 0, 0, 0);
        }
      }
      const int t = cur; cur = nxt; nxt = t;  // swap stage sets
    }

    // ---- epilogue: vals[b][s][h*64+d] single bf16; l = Oe row sum.
    // Row 2047 (fully masked -> exactly uniform) = mean(V), from Vsum (phase B).
#pragma unroll
    for (int r = 0; r < 4; ++r) {
      const float inv = 1.0f / Oe[r];
      const int s = rb + quad * 4 + r;
      const size_t rowoff = ((size_t)b * 2048 + s) * 1024 + h * 64;
#pragma unroll
      for (int dt = 0; dt < 4; ++dt) {
        float val = O[dt][r] * inv;
        if (fixw && ph == 1 && quad == 3 && r == 3)  // s == 2047
          val = Vsum[dt][3] * (1.0f / 2048.0f);
        vals[rowoff + dt * 16 + l15] = f2bf(val);
      }
    }
    __syncthreads();  // seal all stage reads before next phase's prologue DMA
  }
}

// ---------------------------------------------------------------------------
// ws (64 MB): qh[0,8) kh[8,16) vth[16,24) vals[24,32)
// wqh[48,54) wql[54,60) woh[60,62) wol[62,64).
// d_out: xh[0,8) (dead after gemm_qkv); gemm_out2 writes final fp32 directly.
// ---------------------------------------------------------------------------
extern "C" void kernel_launch(void* const* d_in, const int* in_sizes, int n_in,
                              void* d_out, int out_size, void* d_ws, size_t ws_size,
                              hipStream_t stream) {
  const float* x    = (const float*)d_in[0];
  const float* Wqkv = (const float*)d_in[1];
  const float* bqkv = (const float*)d_in[2];
  const float* Wout = (const float*)d_in[3];
  const float* bout = (const float*)d_in[4];
  float* out = (float*)d_out;
  char* wsb = (char*)d_ws;

  unsigned short* qhp  = (unsigned short*)d_ws;
  unsigned short* khp  = qhp + 1 * 4194304;
  unsigned short* vthp = qhp + 2 * 4194304;
  unsigned short* vals = qhp + 3 * 4194304;
  unsigned short* wqh  = (unsigned short*)(wsb + (48u << 20));
  unsigned short* wql  = (unsigned short*)(wsb + (54u << 20));
  unsigned short* woh  = (unsigned short*)(wsb + (60u << 20));
  unsigned short* wol  = (unsigned short*)(wsb + (62u << 20));
  unsigned short* xh   = (unsigned short*)d_out;

  dim3 blk(256);
  split_all<<<8192, blk, 0, stream>>>(x, xh, Wqkv, wqh, wql, Wout, woh, wol);
  gemm_qkv<<<dim3(32, 24), blk, 0, stream>>>(xh, wqh, wql, bqkv, qhp, khp, vthp);
  attn_2ph<<<dim3(32, 16), blk, 0, stream>>>(qhp, khp, vthp, vals);
  gemm_out2<<<dim3(32, 16), blk, 0, stream>>>(vals, woh, wol, bout, out);
}

// Round 14
// 199.865 us; speedup vs baseline: 1.0477x; 1.0032x over previous
//
#include <hip/hip_runtime.h>
#include <hip/hip_bf16.h>
#include <math.h>

#define Bb 2
#define Ss 2048
#define Ee 1024
#define Hh 16
#define HDd 64
#define NEG_INF_F -1000000000.0f

typedef __attribute__((ext_vector_type(8))) short bfrag;     // 8 bf16
typedef __attribute__((ext_vector_type(4))) float ffrag;     // 16x16 C/D
typedef __attribute__((ext_vector_type(16))) float ffrag16;  // 32x32 C/D
typedef __attribute__((ext_vector_type(8))) unsigned short us8;

#define C1F 0.1803368801f  /* 0.125 * log2(e) — folded into Q at gemm_qkv */

// ---- bf16 helpers ----------------------------------------------------------
__device__ __forceinline__ unsigned short f2bf(float x) {
  unsigned u = __float_as_uint(x);
  u += 0x7fffu + ((u >> 16) & 1u);
  return (unsigned short)(u >> 16);
}
__device__ __forceinline__ float bf2f(unsigned short h) {
  return __uint_as_float(((unsigned)h) << 16);
}

__device__ __forceinline__ void async_copy16(void* lds, const void* g) {
  __builtin_amdgcn_global_load_lds(
      (const __attribute__((address_space(1))) unsigned int*)g,
      (__attribute__((address_space(3))) unsigned int*)lds, 16, 0, 0);
}

// ---------------------------------------------------------------------------
// Fused split pass: x (4M) -> hi only; Wqkv (3M), Wout (1M) -> hi/lo.
// ---------------------------------------------------------------------------
__global__ __launch_bounds__(256) void split_all(
    const float* __restrict__ x, unsigned short* __restrict__ xh,
    const float* __restrict__ wq, unsigned short* __restrict__ wqh,
    unsigned short* __restrict__ wql,
    const float* __restrict__ wo, unsigned short* __restrict__ woh,
    unsigned short* __restrict__ wol) {
  int bid = blockIdx.x;
  const float* in;
  unsigned short *hi, *lo;
  if (bid < 4096) { in = x; hi = xh; lo = nullptr; }
  else if (bid < 7168) { bid -= 4096; in = wq; hi = wqh; lo = wql; }
  else { bid -= 7168; in = wo; hi = woh; lo = wol; }
  const int idx = (bid * 256 + threadIdx.x) * 4;
  const float4 v = *(const float4*)(in + idx);
  unsigned short h0 = f2bf(v.x), h1 = f2bf(v.y), h2 = f2bf(v.z), h3 = f2bf(v.w);
  ushort4 hv = {h0, h1, h2, h3};
  *(ushort4*)(hi + idx) = hv;
  if (lo) {
    ushort4 lv = {f2bf(v.x - bf2f(h0)), f2bf(v.y - bf2f(h1)),
                  f2bf(v.z - bf2f(h2)), f2bf(v.w - bf2f(h3))};
    *(ushort4*)(lo + idx) = lv;
  }
}

// ---------------------------------------------------------------------------
// LDS slot map (rows of 32 bf16 = 4 x 16B chunks):
// slot(row,q) = (row>>1)*8 + ((((row&1)*4)|q) ^ ((row>>1)&7)).
// ---------------------------------------------------------------------------
__device__ __forceinline__ int gemm_slot(int row, int q) {
  return (row >> 1) * 8 + ((((row & 1) * 4) | q) ^ ((row >> 1) & 7));
}
__device__ __forceinline__ int slot_src_off(int slot, int ld) {
  const int dr = slot >> 3;
  const int idx8 = (slot & 7) ^ (dr & 7);
  const int row = dr * 2 + (idx8 >> 2);
  const int q = idx8 & 3;
  return row * ld + q * 8;
}

// ---------------------------------------------------------------------------
// QKV GEMM, 32x32x16 core: C = xh * (Wh + Wl)^T + bias (2 MFMAs/product).
// 128x128 tile, BK=64 single-buffered (R13 measured: 62.7 -> 60.4us, total
// -2.0us): 16 K-iterations of {sync; stage 12 DMAs (two 32-col sub-tiles
// per matrix); sync; per sub-tile: read 12 frags + 16 MFMAs}. Halves the
// exposed DMA-drain count vs BK=32 while keeping LDS at 48KB -> 3 blocks/CU
// (grid 768 = 3/CU) and register peak flat.
// Epilogue (all single bf16): Q pre-scaled by C1F -> [bh][s][64];
// K -> [bh][s][64]; V^T -> [bh][d][s].
// ---------------------------------------------------------------------------
__global__ __launch_bounds__(256) void gemm_qkv(
    const unsigned short* __restrict__ Ah,
    const unsigned short* __restrict__ Bh, const unsigned short* __restrict__ Bl,
    const float* __restrict__ bias,
    unsigned short* __restrict__ q_h, unsigned short* __restrict__ k_h,
    unsigned short* __restrict__ vt_h) {
  __shared__ unsigned short sm[3 * 8192];  // 3 matrices x (2 x 32-col sub-tile) = 48KB
  const int tid = threadIdx.x;
  const int lane = tid & 63;
  const int w = tid >> 6;
  const int wm = w >> 1;
  const int wn = w & 1;
  const int l31 = lane & 31;
  const int e = lane >> 5;
  const int m0 = blockIdx.x * 128;
  const int n0 = blockIdx.y * 128;

  int coff[2], ldsb[2];
#pragma unroll
  for (int u = 0; u < 2; ++u) {
    const int slot = w * 128 + u * 64 + lane;
    coff[u] = slot_src_off(slot, 1024);
    ldsb[u] = (w * 128 + u * 64) * 8;
  }
  const unsigned short* srcs[3] = {
      Ah + (size_t)m0 * 1024, Bh + (size_t)n0 * 1024, Bl + (size_t)n0 * 1024};

  ffrag16 acc[2][2];
#pragma unroll
  for (int i = 0; i < 2; ++i)
#pragma unroll
    for (int j = 0; j < 2; ++j) acc[i][j] = (ffrag16)0.f;

  int ca[2][2], cb[2][2];
#pragma unroll
  for (int t = 0; t < 2; ++t)
#pragma unroll
    for (int h2 = 0; h2 < 2; ++h2) {
      ca[t][h2] = gemm_slot(wm * 64 + t * 32 + l31, h2 * 2 + e) * 8;
      cb[t][h2] = gemm_slot(wn * 64 + t * 32 + l31, h2 * 2 + e) * 8;
    }

  for (int k0 = 0; k0 < 1024; k0 += 64) {
    __syncthreads();
#pragma unroll
    for (int t = 0; t < 3; ++t)
#pragma unroll
      for (int s = 0; s < 2; ++s)
#pragma unroll
        for (int u = 0; u < 2; ++u)
          async_copy16(&sm[t * 8192 + s * 4096 + ldsb[u]],
                       srcs[t] + coff[u] + k0 + s * 32);
    __syncthreads();

#pragma unroll
    for (int s = 0; s < 2; ++s) {
      const int sb = s * 4096;
      bfrag ah[2][2], bhf[2][2], blf[2][2];
#pragma unroll
      for (int t = 0; t < 2; ++t)
#pragma unroll
        for (int h2 = 0; h2 < 2; ++h2) {
          ah[t][h2] = *(const bfrag*)&sm[0 * 8192 + sb + ca[t][h2]];
          bhf[t][h2] = *(const bfrag*)&sm[1 * 8192 + sb + cb[t][h2]];
          blf[t][h2] = *(const bfrag*)&sm[2 * 8192 + sb + cb[t][h2]];
        }
#pragma unroll
      for (int mt = 0; mt < 2; ++mt)
#pragma unroll
        for (int nt = 0; nt < 2; ++nt)
#pragma unroll
          for (int h2 = 0; h2 < 2; ++h2) {
            acc[mt][nt] = __builtin_amdgcn_mfma_f32_32x32x16_bf16(
                ah[mt][h2], bhf[nt][h2], acc[mt][nt], 0, 0, 0);
            acc[mt][nt] = __builtin_amdgcn_mfma_f32_32x32x16_bf16(
                ah[mt][h2], blf[nt][h2], acc[mt][nt], 0, 0, 0);
          }
    }
  }

#pragma unroll
  for (int nt = 0; nt < 2; ++nt) {
    const int n = n0 + wn * 64 + nt * 32 + l31;
    const float bv = bias[n];
    const int h = n / 192;
    const int c = n - h * 192;
    const int d = c & 63;
#pragma unroll
    for (int mt = 0; mt < 2; ++mt) {
      if (c >= 128) {
#pragma unroll
        for (int g = 0; g < 4; ++g) {
          const int m = m0 + wm * 64 + mt * 32 + g * 8 + e * 4;
          const int bidx = m >> 11;
          const int s = m & 2047;
          ushort4 hv4;
          unsigned short* ph = (unsigned short*)&hv4;
#pragma unroll
          for (int r = 0; r < 4; ++r)
            ph[r] = f2bf(acc[mt][nt][g * 4 + r] + bv);
          const size_t off =
              (size_t)(bidx * 16 + h) * (64 * 2048) + (size_t)d * 2048 + s;
          *(ushort4*)(vt_h + off) = hv4;
        }
      } else {
        const float scale = (c < 64) ? C1F : 1.0f;
        unsigned short* dh = (c < 64) ? q_h : k_h;
#pragma unroll
        for (int g = 0; g < 4; ++g)
#pragma unroll
          for (int r = 0; r < 4; ++r) {
            const int m = m0 + wm * 64 + mt * 32 + g * 8 + e * 4 + r;
            const int bidx = m >> 11;
            const int s = m & 2047;
            const size_t off =
                (size_t)(bidx * 16 + h) * (2048 * 64) + (size_t)s * 64 + d;
            dh[off] = f2bf((acc[mt][nt][g * 4 + r] + bv) * scale);
          }
      }
    }
  }
}

// ---------------------------------------------------------------------------
// Out-proj GEMM: A = vals single bf16, B = Wout hi/lo (2 MFMAs/product).
// 128x64 tile, 512 blocks. BK=64 single-buffered (R14 — same proven
// mechanism as R13's gemm_qkv): 16 K-iterations, 8 DMAs each (two 32-col
// sub-tiles); halves barrier-drain count. LDS 32KB; grid-limited at
// 2 blocks/CU so the extra LDS is free. Writes fp32+bias directly to out.
// ---------------------------------------------------------------------------
__global__ __launch_bounds__(256) void gemm_out2(
    const unsigned short* __restrict__ A,
    const unsigned short* __restrict__ Bh, const unsigned short* __restrict__ Bl,
    const float* __restrict__ bias, float* __restrict__ out) {
  __shared__ unsigned short sm[16384];  // A[0,8192) Bh[8192,12288) Bl[12288,16384)
  const int tid = threadIdx.x;
  const int lane = tid & 63;
  const int w = tid >> 6;
  const int wm = w >> 1;
  const int wn = w & 1;
  const int l31 = lane & 31;
  const int e = lane >> 5;
  const int m0 = blockIdx.x * 128;
  const int n0 = blockIdx.y * 64;

  int acoff[2], aldsb[2];
#pragma unroll
  for (int u = 0; u < 2; ++u) {
    const int slot = w * 128 + u * 64 + lane;
    acoff[u] = slot_src_off(slot, 1024);
    aldsb[u] = (w * 128 + u * 64) * 8;
  }
  const int bslot = w * 64 + lane;
  const int bcoff = slot_src_off(bslot, 1024);
  const int bldsb = bslot * 8;

  const unsigned short* Ap  = A + (size_t)m0 * 1024;
  const unsigned short* Bph = Bh + (size_t)n0 * 1024;
  const unsigned short* Bpl = Bl + (size_t)n0 * 1024;

  ffrag16 acc[2];
  acc[0] = (ffrag16)0.f;
  acc[1] = (ffrag16)0.f;

  int ca[2][2], cb[2];
#pragma unroll
  for (int t = 0; t < 2; ++t)
#pragma unroll
    for (int h2 = 0; h2 < 2; ++h2)
      ca[t][h2] = gemm_slot(wm * 64 + t * 32 + l31, h2 * 2 + e) * 8;
#pragma unroll
  for (int h2 = 0; h2 < 2; ++h2)
    cb[h2] = gemm_slot(wn * 32 + l31, h2 * 2 + e) * 8;

  for (int k0 = 0; k0 < 1024; k0 += 64) {
    __syncthreads();
#pragma unroll
    for (int s = 0; s < 2; ++s) {
#pragma unroll
      for (int u = 0; u < 2; ++u)
        async_copy16(&sm[0 + s * 4096 + aldsb[u]], Ap + acoff[u] + k0 + s * 32);
      async_copy16(&sm[8192 + s * 2048 + bldsb], Bph + bcoff + k0 + s * 32);
      async_copy16(&sm[12288 + s * 2048 + bldsb], Bpl + bcoff + k0 + s * 32);
    }
    __syncthreads();

#pragma unroll
    for (int s = 0; s < 2; ++s) {
      bfrag ah[2][2], bhf[2], blf[2];
#pragma unroll
      for (int t = 0; t < 2; ++t)
#pragma unroll
        for (int h2 = 0; h2 < 2; ++h2)
          ah[t][h2] = *(const bfrag*)&sm[0 + s * 4096 + ca[t][h2]];
#pragma unroll
      for (int h2 = 0; h2 < 2; ++h2) {
        bhf[h2] = *(const bfrag*)&sm[8192 + s * 2048 + cb[h2]];
        blf[h2] = *(const bfrag*)&sm[12288 + s * 2048 + cb[h2]];
      }
#pragma unroll
      for (int mt = 0; mt < 2; ++mt)
#pragma unroll
        for (int h2 = 0; h2 < 2; ++h2) {
          acc[mt] = __builtin_amdgcn_mfma_f32_32x32x16_bf16(
              ah[mt][h2], bhf[h2], acc[mt], 0, 0, 0);
          acc[mt] = __builtin_amdgcn_mfma_f32_32x32x16_bf16(
              ah[mt][h2], blf[h2], acc[mt], 0, 0, 0);
        }
    }
  }

  const int n = n0 + wn * 32 + l31;
  const float bv = bias[n];
#pragma unroll
  for (int mt = 0; mt < 2; ++mt)
#pragma unroll
    for (int g = 0; g < 4; ++g)
#pragma unroll
      for (int r = 0; r < 4; ++r) {
        const int m = m0 + wm * 64 + mt * 32 + g * 8 + e * 4 + r;
        out[(size_t)m * 1024 + n] = acc[mt][g * 4 + r] + bv;
      }
}

// ---------------------------------------------------------------------------
// Two-phase balanced flash attention, double-buffered LDS staging (R3 form —
// best measured across R3/R8/R10 variants). Each block runs row-block y
// (span 32-y) then 31-y (span y+1): uniform 33-iter span; 40KB LDS.
// Row 2047 fixup on (y=0,w=3): Vsum in phase A, owns row 2047 in phase B.
// ---------------------------------------------------------------------------
__global__ __launch_bounds__(256, 4) void attn_2ph(
    const unsigned short* __restrict__ qh, const unsigned short* __restrict__ kh,
    const unsigned short* __restrict__ vth, unsigned short* __restrict__ vals) {
  __shared__ unsigned short sm[2 * 8192 + 4096];  // 2 stage sets (K+V) + P = 40KB
  const int tid = threadIdx.x;
  const int lane = tid & 63;
  const int w = tid >> 6;
  const int l15 = lane & 15;
  const int quad = lane >> 4;
  const int bh = blockIdx.x;
  const int y = blockIdx.y;
  const size_t base = (size_t)bh * (Ss * HDd);
  const int b = bh >> 4;
  const int h = bh & 15;
  const int PB = 16384;  // P region base (shorts)

  // staging offsets (same swizzled slot map as R0)
  const int c0 = w * 128 + lane;
  const int c1 = c0 + 64;
  const int r0 = c0 >> 3, r1 = c1 >> 3;
  const int s0 = ((c0 & 7) ^ (r0 & 7)) * 8;
  const int s1 = ((c1 & 7) ^ (r1 & 7)) * 8;
  const int koff0 = r0 * 64 + s0, koff1 = r1 * 64 + s1;
  const int voff0 = r0 * 2048 + s0, voff1 = r1 * 2048 + s1;
  const int ldsc0 = c0 * 8;
  const int ldsc1 = c1 * 8;

  bfrag vone;
#pragma unroll
  for (int j = 0; j < 8; ++j) vone[j] = (short)0x3F80;  // bf16 1.0

  const bool fixw = (y == 0) && (w == 3);  // phase A sees all kt; phase B owns row 2047
  ffrag Vsum[4];
#pragma unroll
  for (int dt = 0; dt < 4; ++dt) Vsum[dt] = (ffrag)0.f;

  for (int ph = 0; ph < 2; ++ph) {
    const int ybk = ph ? (31 - y) : y;
    const int rb = 64 * ybk + 16 * w;  // this wave's 16 query rows

    // Q fragments (Q pre-scaled by 0.125*log2e at gemm_qkv)
    bfrag Qf[2];
#pragma unroll
    for (int ks = 0; ks < 2; ++ks)
      Qf[ks] = *(const bfrag*)(qh + base + (size_t)(rb + l15) * 64 + ks * 32 + quad * 8);

    ffrag O[4], Oe;
#pragma unroll
    for (int dt = 0; dt < 4; ++dt) O[dt] = (ffrag)0.f;
    Oe = (ffrag)0.f;

    int cur = 0, nxt = 8192;  // short offsets of the two stage sets
    {  // prologue: stage tile ybk into cur
      const unsigned short* kp = kh + base + ybk * 4096;
      const unsigned short* vp = vth + base + ybk * 64;
      async_copy16(&sm[cur + ldsc0], kp + koff0);
      async_copy16(&sm[cur + ldsc1], kp + koff1);
      async_copy16(&sm[cur + 4096 + ldsc0], vp + voff0);
      async_copy16(&sm[cur + 4096 + ldsc1], vp + voff1);
    }

    for (int kt = ybk; kt < 32; ++kt) {
      __syncthreads();  // drains own DMA (vmcnt 0) + seals nxt for overwrite
      if (kt + 1 < 32) {  // prefetch next tile into nxt (covered by compute)
        const unsigned short* kp = kh + base + (kt + 1) * 4096;
        const unsigned short* vp = vth + base + (kt + 1) * 64;
        async_copy16(&sm[nxt + ldsc0], kp + koff0);
        async_copy16(&sm[nxt + ldsc1], kp + koff1);
        async_copy16(&sm[nxt + 4096 + ldsc0], vp + voff0);
        async_copy16(&sm[nxt + 4096 + ldsc1], vp + voff1);
      }

      // ---- S = Q K^T (Q pre-scaled; K single bf16 from LDS)
      ffrag S[4];
#pragma unroll
      for (int nt = 0; nt < 4; ++nt) S[nt] = (ffrag)0.f;
#pragma unroll
      for (int nt = 0; nt < 4; ++nt) {
        const int krow = nt * 16 + l15;
#pragma unroll
        for (int ks = 0; ks < 2; ++ks) {
          const bfrag kbh =
              *(const bfrag*)&sm[cur + krow * 64 + ((ks * 4 + quad) ^ (krow & 7)) * 8];
          S[nt] = __builtin_amdgcn_mfma_f32_16x16x32_bf16(Qf[ks], kbh, S[nt], 0, 0, 0);
        }
      }

      // ---- p = exp2(S [+ CM if masked]); packed bf16 cvt; store to P LDS
      const float CM = -1.442695041e9f;  // -1e9 * log2(e)
      const bool partial = (kt == ybk);
#pragma unroll
      for (int nt = 0; nt < 4; ++nt) {
        const int key = nt * 16 + l15;
#pragma unroll
        for (int rp = 0; rp < 2; ++rp) {
          float t0 = S[nt][2 * rp];
          float t1 = S[nt][2 * rp + 1];
          if (partial) {
            const int jg = kt * 64 + key;
            const int ig = rb + quad * 4 + 2 * rp;
            if (jg <= ig) t0 += CM;
            if (jg <= ig + 1) t1 += CM;
          }
          float2 pf;
          pf.x = __builtin_amdgcn_exp2f(t0);
          pf.y = __builtin_amdgcn_exp2f(t1);
          const __hip_bfloat162 pb = __float22bfloat162_rn(pf);
          const unsigned short* pbs = (const unsigned short*)&pb;
          const int pr0 = w * 16 + quad * 4 + 2 * rp;
          sm[PB + pr0 * 64 + (((key >> 3) ^ (pr0 & 7)) * 8 + (key & 7))] = pbs[0];
          const int pr1 = pr0 + 1;
          sm[PB + pr1 * 64 + (((key >> 3) ^ (pr1 & 7)) * 8 + (key & 7))] = pbs[1];
        }
      }

      // ---- PV (V single bf16 from LDS) + l via ones-MFMA (+ Vsum, fix wave)
#pragma unroll
      for (int ks = 0; ks < 2; ++ks) {
        const int prow = w * 16 + l15;
        const bfrag pA =
            *(const bfrag*)&sm[PB + prow * 64 + ((ks * 4 + quad) ^ (prow & 7)) * 8];
        Oe = __builtin_amdgcn_mfma_f32_16x16x32_bf16(pA, vone, Oe, 0, 0, 0);
#pragma unroll
        for (int dt = 0; dt < 4; ++dt) {
          const int vrow = dt * 16 + l15;
          const bfrag vbh =
              *(const bfrag*)&sm[cur + 4096 + vrow * 64 + ((ks * 4 + quad) ^ (vrow & 7)) * 8];
          O[dt] = __builtin_amdgcn_mfma_f32_16x16x32_bf16(pA, vbh, O[dt], 0, 0, 0);
          if (fixw && ph == 0)
            Vsum[dt] = __builtin_amdgcn_mfma_f32_16x16x32_bf16(vone, vbh, Vsum[dt], 0, 0, 0);
        }
      }
      const int t = cur; cur = nxt; nxt = t;  // swap stage sets
    }

    // ---- epilogue: vals[b][s][h*64+d] single bf16; l = Oe row sum.
    // Row 2047 (fully masked -> exactly uniform) = mean(V), from Vsum (phase B).
#pragma unroll
    for (int r = 0; r < 4; ++r) {
      const float inv = 1.0f / Oe[r];
      const int s = rb + quad * 4 + r;
      const size_t rowoff = ((size_t)b * 2048 + s) * 1024 + h * 64;
#pragma unroll
      for (int dt = 0; dt < 4; ++dt) {
        float val = O[dt][r] * inv;
        if (fixw && ph == 1 && quad == 3 && r == 3)  // s == 2047
          val = Vsum[dt][3] * (1.0f / 2048.0f);
        vals[rowoff + dt * 16 + l15] = f2bf(val);
      }
    }
    __syncthreads();  // seal all stage reads before next phase's prologue DMA
  }
}

// ---------------------------------------------------------------------------
// ws (64 MB): qh[0,8) kh[8,16) vth[16,24) vals[24,32)
// wqh[48,54) wql[54,60) woh[60,62) wol[62,64).
// d_out: xh[0,8) (dead after gemm_qkv); gemm_out2 writes final fp32 directly.
// ---------------------------------------------------------------------------
extern "C" void kernel_launch(void* const* d_in, const int* in_sizes, int n_in,
                              void* d_out, int out_size, void* d_ws, size_t ws_size,
                              hipStream_t stream) {
  const float* x    = (const float*)d_in[0];
  const float* Wqkv = (const float*)d_in[1];
  const float* bqkv = (const float*)d_in[2];
  const float* Wout = (const float*)d_in[3];
  const float* bout = (const float*)d_in[4];
  float* out = (float*)d_out;
  char* wsb = (char*)d_ws;

  unsigned short* qhp  = (unsigned short*)d_ws;
  unsigned short* khp  = qhp + 1 * 4194304;
  unsigned short* vthp = qhp + 2 * 4194304;
  unsigned short* vals = qhp + 3 * 4194304;
  unsigned short* wqh  = (unsigned short*)(wsb + (48u << 20));
  unsigned short* wql  = (unsigned short*)(wsb + (54u << 20));
  unsigned short* woh  = (unsigned short*)(wsb + (60u << 20));
  unsigned short* wol  = (unsigned short*)(wsb + (62u << 20));
  unsigned short* xh   = (unsigned short*)d_out;

  dim3 blk(256);
  split_all<<<8192, blk, 0, stream>>>(x, xh, Wqkv, wqh, wql, Wout, woh, wol);
  gemm_qkv<<<dim3(32, 24), blk, 0, stream>>>(xh, wqh, wql, bqkv, qhp, khp, vthp);
  attn_2ph<<<dim3(32, 16), blk, 0, stream>>>(qhp, khp, vthp, vals);
  gemm_out2<<<dim3(32, 16), blk, 0, stream>>>(vals, woh, wol, bout, out);
}